// Round 12
// baseline (329.496 us; speedup 1.0000x reference)
//
#include <hip/hip_runtime.h>
#include <hip/hip_bf16.h>
#include <stdint.h>

#define N_DIM 4
#define FIN 32
#define FOUT 64
#define ROWLEN 128   // FIN * N_DIM
#define NBLK 512     // edge chunks for the counting sort
#define BMAX 512     // max buckets (rows/256), M <= 131072
#define MAXE 20      // bsort: register-staged entries per thread

typedef __attribute__((ext_vector_type(4))) float f32x4;
typedef __attribute__((ext_vector_type(8))) short bf16x8;

__device__ __forceinline__ ushort f32_to_bf16_rn(float f) {
  uint u = __float_as_uint(f);
  u += 0x7FFFu + ((u >> 16) & 1u);     // round-to-nearest-even
  return (ushort)(u >> 16);
}
__device__ __forceinline__ float bf16_lo(uint p) { return __uint_as_float(p << 16); }
__device__ __forceinline__ float bf16_hi(uint p) { return __uint_as_float(p & 0xFFFF0000u); }

// ---------------------------------------------------------------------------
// 1. Fused: transpose x[N][M][Fin] -> Tb0[m][n*32+f] (bf16)  +  bcount.
// ---------------------------------------------------------------------------
__global__ __launch_bounds__(256) void trans_count_kernel(
    const float* __restrict__ x, ushort* __restrict__ Tb0, int M, int tblocks,
    const int* __restrict__ rows, int* __restrict__ c, int E, int B, int ce) {
  __shared__ int hist[BMAX];
  if (blockIdx.x >= (unsigned)tblocks) {
    int blk = blockIdx.x - tblocks;
    int tid = threadIdx.x;
    for (int b = tid; b < B; b += 256) hist[b] = 0;
    __syncthreads();
    int start = blk * ce;
    int end = min(E, start + ce);
    for (int e = start + tid; e < end; e += 256)
      atomicAdd(&hist[rows[e] >> 8], 1);
    __syncthreads();
    for (int b = tid; b < B; b += 256) c[blk * B + b] = hist[b];
    return;
  }
  int i = blockIdx.x * blockDim.x + threadIdx.x;
  if (i >= M * 16) return;
  int m = i >> 4;
  int n = (i >> 2) & 3;
  int f8 = i & 3;
  const float* src = x + ((size_t)n * M + m) * FIN + f8 * 8;
  float4 v0 = *reinterpret_cast<const float4*>(src);
  float4 v1 = *reinterpret_cast<const float4*>(src + 4);
  ushort h[8];
  h[0] = f32_to_bf16_rn(v0.x); h[1] = f32_to_bf16_rn(v0.y);
  h[2] = f32_to_bf16_rn(v0.z); h[3] = f32_to_bf16_rn(v0.w);
  h[4] = f32_to_bf16_rn(v1.x); h[5] = f32_to_bf16_rn(v1.y);
  h[6] = f32_to_bf16_rn(v1.z); h[7] = f32_to_bf16_rn(v1.w);
  *reinterpret_cast<uint4*>(Tb0 + (size_t)m * ROWLEN + n * 32 + f8 * 8) =
      *reinterpret_cast<const uint4*>(h);
}

// ---------------------------------------------------------------------------
// 2a. Per-bucket exclusive scan over the NBLK chunk counts.
// ---------------------------------------------------------------------------
__global__ __launch_bounds__(NBLK) void bscanA_kernel(
    const int* __restrict__ c, int* __restrict__ cs,
    int* __restrict__ btot, int B) {
  __shared__ int wsum[8];
  int b = blockIdx.x, tid = threadIdx.x;
  int lane = tid & 63, wid = tid >> 6;
  int v = c[tid * B + b];
  int s = v;
#pragma unroll
  for (int off = 1; off < 64; off <<= 1) {
    int u = __shfl_up(s, off);
    if (lane >= off) s += u;
  }
  if (lane == 63) wsum[wid] = s;
  __syncthreads();
  if (tid == 0) {
    int run = 0;
#pragma unroll
    for (int w = 0; w < 8; ++w) { int t = wsum[w]; wsum[w] = run; run += t; }
  }
  __syncthreads();
  int excl = wsum[wid] + s - v;
  cs[b * NBLK + tid] = excl;
  if (tid == NBLK - 1) btot[b] = excl + v;
}

// ---------------------------------------------------------------------------
// 2b. bscatter: local rescan of btot -> bucket starts, block-private append.
// ---------------------------------------------------------------------------
__global__ __launch_bounds__(256) void bscatter_kernel(
    const int* __restrict__ rows, const int* __restrict__ cols,
    const float* __restrict__ vals, const int* __restrict__ cs,
    const int* __restrict__ btot, int2* __restrict__ binned,
    int E, int B, int ce) {
  __shared__ int bstart[BMAX];
  __shared__ int base[BMAX];
  __shared__ int lcur[BMAX];
  __shared__ int wsum[4];
  int tid = threadIdx.x, blk = blockIdx.x;
  int lane = tid & 63, wid = tid >> 6;
  int i0 = 2 * tid, i1 = 2 * tid + 1;
  int v0 = (i0 < B) ? btot[i0] : 0;
  int v1 = (i1 < B) ? btot[i1] : 0;
  int ps = v0 + v1;
  int s = ps;
#pragma unroll
  for (int off = 1; off < 64; off <<= 1) {
    int u = __shfl_up(s, off);
    if (lane >= off) s += u;
  }
  if (lane == 63) wsum[wid] = s;
  __syncthreads();
  if (tid == 0) {
    int run = 0;
#pragma unroll
    for (int w = 0; w < 4; ++w) { int t = wsum[w]; wsum[w] = run; run += t; }
  }
  __syncthreads();
  int excl = wsum[wid] + s - ps;
  bstart[i0] = excl;
  bstart[i1] = excl + v0;
  __syncthreads();
  for (int b = tid; b < B; b += 256) {
    base[b] = bstart[b] + cs[b * NBLK + blk];
    lcur[b] = 0;
  }
  __syncthreads();
  int start = blk * ce;
  int end = min(E, start + ce);
  for (int e = start + tid; e < end; e += 256) {
    int r = rows[e];
    int b = r >> 8;
    int pos = atomicAdd(&lcur[b], 1);
    binned[base[b] + pos] =
        make_int2(cols[e] | ((r & 255) << 17), __float_as_int(vals[e]));
  }
}

// ---------------------------------------------------------------------------
// 2c. bsort: one block per bucket; histogram -> scan -> scatter into csr.
// ---------------------------------------------------------------------------
__global__ __launch_bounds__(256) void bsort_kernel(
    const int2* __restrict__ binned, const int* __restrict__ btot,
    int2* __restrict__ csr, int* __restrict__ row_start,
    int M, int B, int E) {
  __shared__ int hist[256];
  __shared__ int wsum[4];
  __shared__ int sbase;
  int b = blockIdx.x, tid = threadIdx.x;
  int lane = tid & 63, wid = tid >> 6;
  hist[tid] = 0;
  if (b == 0 && tid == 0) row_start[M] = E;
  int acc = 0;
  for (int i = tid; i < B; i += 256)
    if (i < b) acc += btot[i];
#pragma unroll
  for (int off = 1; off < 64; off <<= 1) acc += __shfl_xor(acc, off);
  if (lane == 0) wsum[wid] = acc;
  __syncthreads();
  if (tid == 0) sbase = wsum[0] + wsum[1] + wsum[2] + wsum[3];
  __syncthreads();
  int base = sbase;
  int cnt = btot[b];

  int2 en[MAXE];
#pragma unroll
  for (int k = 0; k < MAXE; ++k) {
    int i = tid + k * 256;
    if (i < cnt) {
      en[k] = binned[base + i];
      atomicAdd(&hist[((unsigned)en[k].x) >> 17], 1);
    }
  }
  for (int i = tid + MAXE * 256; i < cnt; i += 256)   // overflow fallback
    atomicAdd(&hist[((unsigned)binned[base + i].x) >> 17], 1);
  __syncthreads();
  int v = hist[tid];
  int s = v;
#pragma unroll
  for (int off = 1; off < 64; off <<= 1) {
    int u = __shfl_up(s, off);
    if (lane >= off) s += u;
  }
  if (lane == 63) wsum[wid] = s;
  __syncthreads();
  if (tid == 0) {
    int run = 0;
#pragma unroll
    for (int w = 0; w < 4; ++w) { int t = wsum[w]; wsum[w] = run; run += t; }
  }
  __syncthreads();
  int excl = wsum[wid] + s - v;
  int r = (b << 8) + tid;
  if (r < M) row_start[r] = base + excl;
  __syncthreads();
  hist[tid] = excl;
  __syncthreads();
#pragma unroll
  for (int k = 0; k < MAXE; ++k) {
    int i = tid + k * 256;
    if (i < cnt) {
      int rl = ((unsigned)en[k].x) >> 17;
      int p = atomicAdd(&hist[rl], 1);
      csr[base + p] = make_int2(en[k].x & 0x1FFFF, en[k].y);
    }
  }
  for (int i = tid + MAXE * 256; i < cnt; i += 256) {
    int2 e2 = binned[base + i];
    int rl = ((unsigned)e2.x) >> 17;
    int p = atomicAdd(&hist[rl], 1);
    csr[base + p] = make_int2(e2.x & 0x1FFFF, e2.y);
  }
}

// ---------------------------------------------------------------------------
// 3. SpMM — wave per row; scalar-pipe edges; 3x8-edge batches in flight
//    (~24 gathers outstanding). 4B/lane gathers.
// ---------------------------------------------------------------------------
#define LOADC(C, base)                                        \
  _Pragma("unroll") for (int u = 0; u < 8; ++u) C[u] = csr[(base) + u];
#define GATH(G, C)                                            \
  _Pragma("unroll") for (int u = 0; u < 8; ++u)               \
      G[u] = srcb[(size_t)(unsigned)C[u].x * 64 + lane];
#define CONS(G, C)                                            \
  _Pragma("unroll") for (int u = 0; u < 8; ++u) {             \
    float v = __int_as_float(C[u].y);                         \
    ax += v * bf16_lo(G[u]);                                  \
    ay += v * bf16_hi(G[u]);                                  \
  }

__global__ __launch_bounds__(256) void spmm_kernel(
    const uint* __restrict__ srcb, const uint* __restrict__ prevb,
    uint* __restrict__ dstb,
    const int* __restrict__ row_start, const int2* __restrict__ csr,
    int M, float alpha, float beta, float gamma) {
  int wid = __builtin_amdgcn_readfirstlane((int)threadIdx.x >> 6);
  int gw = blockIdx.x * 4 + wid;
  int lane = threadIdx.x & 63;
  if (gw >= M) return;
  int s = row_start[gw];
  int e = row_start[gw + 1];
  // self/prev row loads issued up front (independent of the edge loop)
  uint sp = srcb[(size_t)gw * 64 + lane];
  uint pp = prevb ? prevb[(size_t)gw * 64 + lane] : 0u;

  float ax = 0.f, ay = 0.f;
  int j = s;
  int cnt = e - s;
  if (cnt >= 24) {
    int2 c0[8], c1[8], c2[8];
    uint g0[8], g1[8], g2[8];
    LOADC(c0, j);      GATH(g0, c0);
    LOADC(c1, j + 8);  GATH(g1, c1);
    LOADC(c2, j + 16); GATH(g2, c2);
    j += 24;
    for (; j + 24 <= e; j += 24) {
      CONS(g0, c0); LOADC(c0, j);      GATH(g0, c0);
      CONS(g1, c1); LOADC(c1, j + 8);  GATH(g1, c1);
      CONS(g2, c2); LOADC(c2, j + 16); GATH(g2, c2);
    }
    if (j + 16 <= e) {
      CONS(g0, c0); LOADC(c0, j);     GATH(g0, c0);
      CONS(g1, c1); LOADC(c1, j + 8); GATH(g1, c1);
      j += 16;
    } else if (j + 8 <= e) {
      CONS(g0, c0); LOADC(c0, j); GATH(g0, c0);
      j += 8;
    }
    CONS(g0, c0);
    CONS(g1, c1);
    CONS(g2, c2);
  } else if (cnt >= 16) {
    int2 c0[8], c1[8];
    uint g0[8], g1[8];
    LOADC(c0, j);     GATH(g0, c0);
    LOADC(c1, j + 8); GATH(g1, c1);
    j += 16;
    if (j + 8 <= e) {
      CONS(g0, c0); LOADC(c0, j); GATH(g0, c0);
      j += 8;
    }
    CONS(g0, c0);
    CONS(g1, c1);
  } else if (cnt >= 8) {
    int2 c0[8];
    uint g0[8];
    LOADC(c0, j); GATH(g0, c0);
    j += 8;
    CONS(g0, c0);
  }
  for (; j < e; ++j) {
    int2 cv = csr[j];
    uint p = srcb[(size_t)(unsigned)cv.x * 64 + lane];
    float v = __int_as_float(cv.y);
    ax += v * bf16_lo(p);
    ay += v * bf16_hi(p);
  }

  ax = alpha * ax + beta * bf16_lo(sp);
  ay = alpha * ay + beta * bf16_hi(sp);
  if (prevb) {
    ax += gamma * bf16_lo(pp);
    ay += gamma * bf16_hi(pp);
  }
  dstb[(size_t)gw * 64 + lane] =
      (uint)f32_to_bf16_rn(ax) | ((uint)f32_to_bf16_rn(ay) << 16);
}

// ---------------------------------------------------------------------------
// 4. Final GEMM via MFMA 16x16x32 bf16, no LDS (round-6 proven).
// ---------------------------------------------------------------------------
__global__ __launch_bounds__(256) void gemm_kernel(
    const ushort* __restrict__ Tb0, const ushort* __restrict__ Tb1,
    const ushort* __restrict__ Tb2, const ushort* __restrict__ Tb3,
    const float* __restrict__ W, float* __restrict__ out,
    int M, int nwaves) {
  int lane = threadIdx.x & 63;
  int gwave = blockIdx.x * 4 + ((int)threadIdx.x >> 6);
  int g = lane >> 4;   // 0..3: kappa-chunk group / store vertex
  int q = lane & 15;   // A row within tile / output column within fo-tile

  bf16x8 b[4][4];
#pragma unroll
  for (int t = 0; t < 4; ++t) {
#pragma unroll
    for (int ft = 0; ft < 4; ++ft) {
#pragma unroll
      for (int e = 0; e < 8; ++e) {
        float w = W[((8 * g + e) * 4 + t) * FOUT + ft * 16 + q];
        b[t][ft][e] = (short)f32_to_bf16_rn(w);
      }
    }
  }

  int NT = (M + 3) >> 2;
  for (int tile = gwave; tile < NT; tile += nwaves) {
    int m0 = tile * 4;
    int mA = m0 + (q >> 2);
    if (mA > M - 1) mA = M - 1;      // clamp; garbage rows are store-guarded
    int n = q & 3;
    size_t abase = (size_t)mA * ROWLEN + n * 32 + g * 8;

    f32x4 C0 = {0.f, 0.f, 0.f, 0.f};
    f32x4 C1 = C0, C2 = C0, C3 = C0;
#pragma unroll
    for (int t = 0; t < 4; ++t) {
      const ushort* Tb = t == 0 ? Tb0 : t == 1 ? Tb1 : t == 2 ? Tb2 : Tb3;
      bf16x8 a = *reinterpret_cast<const bf16x8*>(Tb + abase);  // 16B aligned
      C0 = __builtin_amdgcn_mfma_f32_16x16x32_bf16(a, b[t][0], C0, 0, 0, 0);
      C1 = __builtin_amdgcn_mfma_f32_16x16x32_bf16(a, b[t][1], C1, 0, 0, 0);
      C2 = __builtin_amdgcn_mfma_f32_16x16x32_bf16(a, b[t][2], C2, 0, 0, 0);
      C3 = __builtin_amdgcn_mfma_f32_16x16x32_bf16(a, b[t][3], C3, 0, 0, 0);
    }
    int mS = m0 + g;
    if (mS < M) {
#pragma unroll
      for (int r = 0; r < 4; ++r) {
        size_t ob = ((size_t)r * M + mS) * FOUT + q;
        out[ob +  0] = C0[r];
        out[ob + 16] = C1[r];
        out[ob + 32] = C2[r];
        out[ob + 48] = C3[r];
      }
    }
  }
}

// ---------------------------------------------------------------------------
extern "C" void kernel_launch(void* const* d_in, const int* in_sizes, int n_in,
                              void* d_out, int out_size, void* d_ws, size_t ws_size,
                              hipStream_t stream) {
  const float* x         = (const float*)d_in[0];
  const float* edge_vals = (const float*)d_in[1];
  const float* W         = (const float*)d_in[2];
  const int* edge_rows   = (const int*)d_in[3];
  const int* edge_cols   = (const int*)d_in[4];
  float* out = (float*)d_out;

  int M = in_sizes[0] / (N_DIM * FIN);
  int E = in_sizes[1];
  int B = (M + 255) >> 8;             // buckets of 256 rows
  int ce = (E + NBLK - 1) / NBLK;     // edges per chunk
  int tblocks = (M * 16 + 255) / 256;

  char* ws = (char*)d_ws;
  size_t rowf = (size_t)M * ROWLEN;
  ushort* Tb0 = (ushort*)ws;
  ushort* Tb1 = Tb0 + rowf;
  ushort* Tb2 = Tb1 + rowf;
  ushort* Tb3 = Tb2 + rowf;
  int2* binned = (int2*)(Tb3 + rowf);
  int2* csr = binned + E;                   // E entries + 24 pad
  int* c = (int*)(csr + E + 24);            // NBLK*B  (chunk-major)
  int* cs = c + (size_t)NBLK * B;           // NBLK*B  (bucket-major, scanned)
  int* btot = cs + (size_t)NBLK * B;        // B
  int* row_start = btot + B;                // M+1

  trans_count_kernel<<<tblocks + NBLK, 256, 0, stream>>>(
      x, Tb0, M, tblocks, edge_rows, c, E, B, ce);
  bscanA_kernel<<<B, NBLK, 0, stream>>>(c, cs, btot, B);
  bscatter_kernel<<<NBLK, 256, 0, stream>>>(edge_rows, edge_cols, edge_vals,
                                            cs, btot, binned, E, B, ce);
  bsort_kernel<<<B, 256, 0, stream>>>(binned, btot, csr, row_start, M, B, E);

  int spmm_blocks = (M + 3) / 4;  // wave per row, 4 waves/block
  // T1 = L'T0
  spmm_kernel<<<spmm_blocks, 256, 0, stream>>>(
      (const uint*)Tb0, nullptr, (uint*)Tb1, row_start, csr,
      M, 1.f, -1.f, 0.f);
  // T2 = 2L'T1 - T0
  spmm_kernel<<<spmm_blocks, 256, 0, stream>>>(
      (const uint*)Tb1, (const uint*)Tb0, (uint*)Tb2, row_start, csr,
      M, 2.f, -2.f, -1.f);
  // T3 = 2L'T2 - T1
  spmm_kernel<<<spmm_blocks, 256, 0, stream>>>(
      (const uint*)Tb2, (const uint*)Tb1, (uint*)Tb3, row_start, csr,
      M, 2.f, -2.f, -1.f);

  int gemm_blocks = 1024;  // 4096 waves, grid-stride over (M+3)/4 tiles
  gemm_kernel<<<gemm_blocks, 256, 0, stream>>>(
      Tb0, Tb1, Tb2, Tb3, W, out, M, gemm_blocks * 4);
}

// Round 13
// 296.583 us; speedup vs baseline: 1.1110x; 1.1110x over previous
//
#include <hip/hip_runtime.h>
#include <hip/hip_bf16.h>
#include <stdint.h>

#define N_DIM 4
#define FIN 32
#define FOUT 64
#define ROWLEN 128   // FIN * N_DIM
#define NBLK 512     // edge chunks for the counting sort
#define BMAX 512     // max buckets (rows/256), M <= 131072
#define MAXE 20      // bsort: register-staged entries per thread

typedef __attribute__((ext_vector_type(4))) float f32x4;
typedef __attribute__((ext_vector_type(8))) short bf16x8;

__device__ __forceinline__ ushort f32_to_bf16_rn(float f) {
  uint u = __float_as_uint(f);
  u += 0x7FFFu + ((u >> 16) & 1u);     // round-to-nearest-even
  return (ushort)(u >> 16);
}
__device__ __forceinline__ float bf16_lo(uint p) { return __uint_as_float(p << 16); }
__device__ __forceinline__ float bf16_hi(uint p) { return __uint_as_float(p & 0xFFFF0000u); }

// ---------------------------------------------------------------------------
// 1. Fused: transpose x[N][M][Fin] -> Tb0[m][n*32+f] (bf16)  +  bcount.
// ---------------------------------------------------------------------------
__global__ __launch_bounds__(256) void trans_count_kernel(
    const float* __restrict__ x, ushort* __restrict__ Tb0, int M, int tblocks,
    const int* __restrict__ rows, int* __restrict__ c, int E, int B, int ce) {
  __shared__ int hist[BMAX];
  if (blockIdx.x >= (unsigned)tblocks) {
    int blk = blockIdx.x - tblocks;
    int tid = threadIdx.x;
    for (int b = tid; b < B; b += 256) hist[b] = 0;
    __syncthreads();
    int start = blk * ce;
    int end = min(E, start + ce);
    for (int e = start + tid; e < end; e += 256)
      atomicAdd(&hist[rows[e] >> 8], 1);
    __syncthreads();
    for (int b = tid; b < B; b += 256) c[blk * B + b] = hist[b];
    return;
  }
  int i = blockIdx.x * blockDim.x + threadIdx.x;
  if (i >= M * 16) return;
  int m = i >> 4;
  int n = (i >> 2) & 3;
  int f8 = i & 3;
  const float* src = x + ((size_t)n * M + m) * FIN + f8 * 8;
  float4 v0 = *reinterpret_cast<const float4*>(src);
  float4 v1 = *reinterpret_cast<const float4*>(src + 4);
  ushort h[8];
  h[0] = f32_to_bf16_rn(v0.x); h[1] = f32_to_bf16_rn(v0.y);
  h[2] = f32_to_bf16_rn(v0.z); h[3] = f32_to_bf16_rn(v0.w);
  h[4] = f32_to_bf16_rn(v1.x); h[5] = f32_to_bf16_rn(v1.y);
  h[6] = f32_to_bf16_rn(v1.z); h[7] = f32_to_bf16_rn(v1.w);
  *reinterpret_cast<uint4*>(Tb0 + (size_t)m * ROWLEN + n * 32 + f8 * 8) =
      *reinterpret_cast<const uint4*>(h);
}

// ---------------------------------------------------------------------------
// 2a. Per-bucket exclusive scan over the NBLK chunk counts.
// ---------------------------------------------------------------------------
__global__ __launch_bounds__(NBLK) void bscanA_kernel(
    const int* __restrict__ c, int* __restrict__ cs,
    int* __restrict__ btot, int B) {
  __shared__ int wsum[8];
  int b = blockIdx.x, tid = threadIdx.x;
  int lane = tid & 63, wid = tid >> 6;
  int v = c[tid * B + b];
  int s = v;
#pragma unroll
  for (int off = 1; off < 64; off <<= 1) {
    int u = __shfl_up(s, off);
    if (lane >= off) s += u;
  }
  if (lane == 63) wsum[wid] = s;
  __syncthreads();
  if (tid == 0) {
    int run = 0;
#pragma unroll
    for (int w = 0; w < 8; ++w) { int t = wsum[w]; wsum[w] = run; run += t; }
  }
  __syncthreads();
  int excl = wsum[wid] + s - v;
  cs[b * NBLK + tid] = excl;
  if (tid == NBLK - 1) btot[b] = excl + v;
}

// ---------------------------------------------------------------------------
// 2b. bscatter: local rescan of btot -> bucket starts, block-private append.
// ---------------------------------------------------------------------------
__global__ __launch_bounds__(256) void bscatter_kernel(
    const int* __restrict__ rows, const int* __restrict__ cols,
    const float* __restrict__ vals, const int* __restrict__ cs,
    const int* __restrict__ btot, int2* __restrict__ binned,
    int E, int B, int ce) {
  __shared__ int bstart[BMAX];
  __shared__ int base[BMAX];
  __shared__ int lcur[BMAX];
  __shared__ int wsum[4];
  int tid = threadIdx.x, blk = blockIdx.x;
  int lane = tid & 63, wid = tid >> 6;
  int i0 = 2 * tid, i1 = 2 * tid + 1;
  int v0 = (i0 < B) ? btot[i0] : 0;
  int v1 = (i1 < B) ? btot[i1] : 0;
  int ps = v0 + v1;
  int s = ps;
#pragma unroll
  for (int off = 1; off < 64; off <<= 1) {
    int u = __shfl_up(s, off);
    if (lane >= off) s += u;
  }
  if (lane == 63) wsum[wid] = s;
  __syncthreads();
  if (tid == 0) {
    int run = 0;
#pragma unroll
    for (int w = 0; w < 4; ++w) { int t = wsum[w]; wsum[w] = run; run += t; }
  }
  __syncthreads();
  int excl = wsum[wid] + s - ps;
  bstart[i0] = excl;
  bstart[i1] = excl + v0;
  __syncthreads();
  for (int b = tid; b < B; b += 256) {
    base[b] = bstart[b] + cs[b * NBLK + blk];
    lcur[b] = 0;
  }
  __syncthreads();
  int start = blk * ce;
  int end = min(E, start + ce);
  for (int e = start + tid; e < end; e += 256) {
    int r = rows[e];
    int b = r >> 8;
    int pos = atomicAdd(&lcur[b], 1);
    binned[base[b] + pos] =
        make_int2(cols[e] | ((r & 255) << 17), __float_as_int(vals[e]));
  }
}

// ---------------------------------------------------------------------------
// 2c. bsort: one block per bucket; histogram -> scan -> scatter into csr.
// ---------------------------------------------------------------------------
__global__ __launch_bounds__(256) void bsort_kernel(
    const int2* __restrict__ binned, const int* __restrict__ btot,
    int2* __restrict__ csr, int* __restrict__ row_start,
    int M, int B, int E) {
  __shared__ int hist[256];
  __shared__ int wsum[4];
  __shared__ int sbase;
  int b = blockIdx.x, tid = threadIdx.x;
  int lane = tid & 63, wid = tid >> 6;
  hist[tid] = 0;
  if (b == 0 && tid == 0) row_start[M] = E;
  int acc = 0;
  for (int i = tid; i < B; i += 256)
    if (i < b) acc += btot[i];
#pragma unroll
  for (int off = 1; off < 64; off <<= 1) acc += __shfl_xor(acc, off);
  if (lane == 0) wsum[wid] = acc;
  __syncthreads();
  if (tid == 0) sbase = wsum[0] + wsum[1] + wsum[2] + wsum[3];
  __syncthreads();
  int base = sbase;
  int cnt = btot[b];

  int2 en[MAXE];
#pragma unroll
  for (int k = 0; k < MAXE; ++k) {
    int i = tid + k * 256;
    if (i < cnt) {
      en[k] = binned[base + i];
      atomicAdd(&hist[((unsigned)en[k].x) >> 17], 1);
    }
  }
  for (int i = tid + MAXE * 256; i < cnt; i += 256)   // overflow fallback
    atomicAdd(&hist[((unsigned)binned[base + i].x) >> 17], 1);
  __syncthreads();
  int v = hist[tid];
  int s = v;
#pragma unroll
  for (int off = 1; off < 64; off <<= 1) {
    int u = __shfl_up(s, off);
    if (lane >= off) s += u;
  }
  if (lane == 63) wsum[wid] = s;
  __syncthreads();
  if (tid == 0) {
    int run = 0;
#pragma unroll
    for (int w = 0; w < 4; ++w) { int t = wsum[w]; wsum[w] = run; run += t; }
  }
  __syncthreads();
  int excl = wsum[wid] + s - v;
  int r = (b << 8) + tid;
  if (r < M) row_start[r] = base + excl;
  __syncthreads();
  hist[tid] = excl;
  __syncthreads();
#pragma unroll
  for (int k = 0; k < MAXE; ++k) {
    int i = tid + k * 256;
    if (i < cnt) {
      int rl = ((unsigned)en[k].x) >> 17;
      int p = atomicAdd(&hist[rl], 1);
      csr[base + p] = make_int2(en[k].x & 0x1FFFF, en[k].y);
    }
  }
  for (int i = tid + MAXE * 256; i < cnt; i += 256) {
    int2 e2 = binned[base + i];
    int rl = ((unsigned)e2.x) >> 17;
    int p = atomicAdd(&hist[rl], 1);
    csr[base + p] = make_int2(e2.x & 0x1FFFF, e2.y);
  }
}

// ---------------------------------------------------------------------------
// 3. SpMM — round-11 proven best (wave per row; scalar-pipe edges;
//    2x8-edge batches in flight; 4B/lane gathers).
// ---------------------------------------------------------------------------
#define LOADC(C, base)                                        \
  _Pragma("unroll") for (int u = 0; u < 8; ++u) C[u] = csr[(base) + u];
#define GATH(G, C)                                            \
  _Pragma("unroll") for (int u = 0; u < 8; ++u)               \
      G[u] = srcb[(size_t)(unsigned)C[u].x * 64 + lane];
#define CONS(G, C)                                            \
  _Pragma("unroll") for (int u = 0; u < 8; ++u) {             \
    float v = __int_as_float(C[u].y);                         \
    ax += v * bf16_lo(G[u]);                                  \
    ay += v * bf16_hi(G[u]);                                  \
  }

__global__ __launch_bounds__(256) void spmm_kernel(
    const uint* __restrict__ srcb, const uint* __restrict__ prevb,
    uint* __restrict__ dstb,
    const int* __restrict__ row_start, const int2* __restrict__ csr,
    int M, float alpha, float beta, float gamma) {
  int wid = __builtin_amdgcn_readfirstlane((int)threadIdx.x >> 6);
  int gw = blockIdx.x * 4 + wid;
  int lane = threadIdx.x & 63;
  if (gw >= M) return;
  int s = row_start[gw];
  int e = row_start[gw + 1];
  // self/prev row loads issued up front (independent of the edge loop)
  uint sp = srcb[(size_t)gw * 64 + lane];
  uint pp = prevb ? prevb[(size_t)gw * 64 + lane] : 0u;

  float ax = 0.f, ay = 0.f;
  int j = s;
  int cnt = e - s;
  if (cnt >= 16) {
    int2 c0[8], c1[8];
    uint g0[8], g1[8];
    LOADC(c0, j); GATH(g0, c0);
    LOADC(c1, j + 8); GATH(g1, c1);
    j += 16;
    for (; j + 16 <= e; j += 16) {
      CONS(g0, c0); LOADC(c0, j); GATH(g0, c0);
      CONS(g1, c1); LOADC(c1, j + 8); GATH(g1, c1);
    }
    if (j + 8 <= e) {
      CONS(g0, c0); LOADC(c0, j); GATH(g0, c0);
      j += 8;
      CONS(g1, c1);
      CONS(g0, c0);
    } else {
      CONS(g0, c0);
      CONS(g1, c1);
    }
  } else if (cnt >= 8) {
    int2 c0[8];
    uint g0[8];
    LOADC(c0, j); GATH(g0, c0);
    j += 8;
    CONS(g0, c0);
  }
  for (; j < e; ++j) {
    int2 cv = csr[j];
    uint p = srcb[(size_t)(unsigned)cv.x * 64 + lane];
    float v = __int_as_float(cv.y);
    ax += v * bf16_lo(p);
    ay += v * bf16_hi(p);
  }

  ax = alpha * ax + beta * bf16_lo(sp);
  ay = alpha * ay + beta * bf16_hi(sp);
  if (prevb) {
    ax += gamma * bf16_lo(pp);
    ay += gamma * bf16_hi(pp);
  }
  dstb[(size_t)gw * 64 + lane] =
      (uint)f32_to_bf16_rn(ax) | ((uint)f32_to_bf16_rn(ay) << 16);
}

// ---------------------------------------------------------------------------
// 4. Final GEMM via MFMA 16x16x32 bf16, no LDS (round-6 proven).
// ---------------------------------------------------------------------------
__global__ __launch_bounds__(256) void gemm_kernel(
    const ushort* __restrict__ Tb0, const ushort* __restrict__ Tb1,
    const ushort* __restrict__ Tb2, const ushort* __restrict__ Tb3,
    const float* __restrict__ W, float* __restrict__ out,
    int M, int nwaves) {
  int lane = threadIdx.x & 63;
  int gwave = blockIdx.x * 4 + ((int)threadIdx.x >> 6);
  int g = lane >> 4;   // 0..3: kappa-chunk group / store vertex
  int q = lane & 15;   // A row within tile / output column within fo-tile

  bf16x8 b[4][4];
#pragma unroll
  for (int t = 0; t < 4; ++t) {
#pragma unroll
    for (int ft = 0; ft < 4; ++ft) {
#pragma unroll
      for (int e = 0; e < 8; ++e) {
        float w = W[((8 * g + e) * 4 + t) * FOUT + ft * 16 + q];
        b[t][ft][e] = (short)f32_to_bf16_rn(w);
      }
    }
  }

  int NT = (M + 3) >> 2;
  for (int tile = gwave; tile < NT; tile += nwaves) {
    int m0 = tile * 4;
    int mA = m0 + (q >> 2);
    if (mA > M - 1) mA = M - 1;      // clamp; garbage rows are store-guarded
    int n = q & 3;
    size_t abase = (size_t)mA * ROWLEN + n * 32 + g * 8;

    f32x4 C0 = {0.f, 0.f, 0.f, 0.f};
    f32x4 C1 = C0, C2 = C0, C3 = C0;
#pragma unroll
    for (int t = 0; t < 4; ++t) {
      const ushort* Tb = t == 0 ? Tb0 : t == 1 ? Tb1 : t == 2 ? Tb2 : Tb3;
      bf16x8 a = *reinterpret_cast<const bf16x8*>(Tb + abase);  // 16B aligned
      C0 = __builtin_amdgcn_mfma_f32_16x16x32_bf16(a, b[t][0], C0, 0, 0, 0);
      C1 = __builtin_amdgcn_mfma_f32_16x16x32_bf16(a, b[t][1], C1, 0, 0, 0);
      C2 = __builtin_amdgcn_mfma_f32_16x16x32_bf16(a, b[t][2], C2, 0, 0, 0);
      C3 = __builtin_amdgcn_mfma_f32_16x16x32_bf16(a, b[t][3], C3, 0, 0, 0);
    }
    int mS = m0 + g;
    if (mS < M) {
#pragma unroll
      for (int r = 0; r < 4; ++r) {
        size_t ob = ((size_t)r * M + mS) * FOUT + q;
        out[ob +  0] = C0[r];
        out[ob + 16] = C1[r];
        out[ob + 32] = C2[r];
        out[ob + 48] = C3[r];
      }
    }
  }
}

// ---------------------------------------------------------------------------
extern "C" void kernel_launch(void* const* d_in, const int* in_sizes, int n_in,
                              void* d_out, int out_size, void* d_ws, size_t ws_size,
                              hipStream_t stream) {
  const float* x         = (const float*)d_in[0];
  const float* edge_vals = (const float*)d_in[1];
  const float* W         = (const float*)d_in[2];
  const int* edge_rows   = (const int*)d_in[3];
  const int* edge_cols   = (const int*)d_in[4];
  float* out = (float*)d_out;

  int M = in_sizes[0] / (N_DIM * FIN);
  int E = in_sizes[1];
  int B = (M + 255) >> 8;             // buckets of 256 rows
  int ce = (E + NBLK - 1) / NBLK;     // edges per chunk
  int tblocks = (M * 16 + 255) / 256;

  char* ws = (char*)d_ws;
  size_t rowf = (size_t)M * ROWLEN;
  ushort* Tb0 = (ushort*)ws;
  ushort* Tb1 = Tb0 + rowf;
  ushort* Tb2 = Tb1 + rowf;
  ushort* Tb3 = Tb2 + rowf;
  int2* binned = (int2*)(Tb3 + rowf);
  int2* csr = binned + E;                   // E entries + 8 pad
  int* c = (int*)(csr + E + 8);             // NBLK*B  (chunk-major)
  int* cs = c + (size_t)NBLK * B;           // NBLK*B  (bucket-major, scanned)
  int* btot = cs + (size_t)NBLK * B;        // B
  int* row_start = btot + B;                // M+1

  trans_count_kernel<<<tblocks + NBLK, 256, 0, stream>>>(
      x, Tb0, M, tblocks, edge_rows, c, E, B, ce);
  bscanA_kernel<<<B, NBLK, 0, stream>>>(c, cs, btot, B);
  bscatter_kernel<<<NBLK, 256, 0, stream>>>(edge_rows, edge_cols, edge_vals,
                                            cs, btot, binned, E, B, ce);
  bsort_kernel<<<B, 256, 0, stream>>>(binned, btot, csr, row_start, M, B, E);

  int spmm_blocks = (M + 3) / 4;  // wave per row, 4 waves/block
  // T1 = L'T0
  spmm_kernel<<<spmm_blocks, 256, 0, stream>>>(
      (const uint*)Tb0, nullptr, (uint*)Tb1, row_start, csr,
      M, 1.f, -1.f, 0.f);
  // T2 = 2L'T1 - T0
  spmm_kernel<<<spmm_blocks, 256, 0, stream>>>(
      (const uint*)Tb1, (const uint*)Tb0, (uint*)Tb2, row_start, csr,
      M, 2.f, -2.f, -1.f);
  // T3 = 2L'T2 - T1
  spmm_kernel<<<spmm_blocks, 256, 0, stream>>>(
      (const uint*)Tb2, (const uint*)Tb1, (uint*)Tb3, row_start, csr,
      M, 2.f, -2.f, -1.f);

  int gemm_blocks = 1024;  // 4096 waves, grid-stride over (M+3)/4 tiles
  gemm_kernel<<<gemm_blocks, 256, 0, stream>>>(
      Tb0, Tb1, Tb2, Tb3, W, out, M, gemm_blocks * 4);
}